// Round 8
// baseline (410.737 us; speedup 1.0000x reference)
//
#include <hip/hip_runtime.h>
#include <cstdint>
#include <cstddef>

#define EPI_QKV  0
#define EPI_F32  2
#define EPI_GELU 3
#define EPI_PART 4

typedef __attribute__((ext_vector_type(8))) short bfrag8;   // 8 bf16 (4 VGPRs)
typedef __attribute__((ext_vector_type(4))) float facc4;    // 4 fp32 acc
typedef __attribute__((ext_vector_type(8))) unsigned short ush8;

struct PtrQuad { unsigned short* p[4]; };
struct Ptr4f  { const float* p[4]; };

__device__ __forceinline__ unsigned short f2b(float x) {
  unsigned int u = __builtin_bit_cast(unsigned int, x);
  u += 0x7FFFu + ((u >> 16) & 1u);   // RNE
  return (unsigned short)(u >> 16);
}
__device__ __forceinline__ float b2f(unsigned short u) {
  unsigned int x = ((unsigned int)u) << 16;
  return __builtin_bit_cast(float, x);
}

__device__ __forceinline__ void gl2lds16(const unsigned short* g, unsigned short* l) {
  __builtin_amdgcn_global_load_lds(
      (const __attribute__((address_space(1))) unsigned int*)g,
      (__attribute__((address_space(3))) unsigned int*)l, 16, 0, 0);
}

// ---- fused prep: fp32->bf16 cvt of x + all 6 weight transposes in ONE launch ----
__device__ __forceinline__ void tr_tile(const float* __restrict__ in,
                                        unsigned short* __restrict__ out,
                                        int K, int N, int bx, int by,
                                        float (*tile)[33], int tid) {
  const int n0 = bx * 32, k0 = by * 32;
  const int tx = tid & 31, ty = tid >> 5;  // ty 0..7
#pragma unroll
  for (int i = 0; i < 32; i += 8)
    tile[ty + i][tx] = in[(size_t)(k0 + ty + i) * N + n0 + tx];
  __syncthreads();
#pragma unroll
  for (int i = 0; i < 32; i += 8)
    out[(size_t)(n0 + ty + i) * K + k0 + tx] = f2b(tile[tx][ty + i]);
}

__global__ __launch_bounds__(256)
void prep_kernel(const float* __restrict__ x, unsigned short* __restrict__ XB,
                 Ptr4f Ws, PtrQuad WTs,
                 const float* __restrict__ W1, unsigned short* __restrict__ W1T,
                 const float* __restrict__ W2, unsigned short* __restrict__ W2T) {
  __shared__ float tile[32][33];
  int b = blockIdx.x;
  const int tid = threadIdx.x;
  if (b < 4096) {                                  // cvt x -> bf16 (float4/ushort4)
    const int i = b * 256 + tid;
    const float4 v = ((const float4*)x)[i];
    ushort4 u;
    u.x = f2b(v.x); u.y = f2b(v.y); u.z = f2b(v.z); u.w = f2b(v.w);
    ((ushort4*)XB)[i] = u;
    return;
  }
  b -= 4096;
  if (b < 4096) {                                  // Wq/Wk/Wv/Wo: 1024x1024 each
    const int which = b >> 10, t = b & 1023;
    tr_tile(Ws.p[which], WTs.p[which], 1024, 1024, t & 31, t >> 5, tile, tid);
    return;
  }
  b -= 4096;
  if (b < 4096) {                                  // W1: K=1024, N=4096
    tr_tile(W1, W1T, 1024, 4096, b & 127, b >> 7, tile, tid);
    return;
  }
  b -= 4096;                                       // W2: K=4096, N=1024
  tr_tile(W2, W2T, 4096, 1024, b & 31, b >> 5, tile, tid);
}

// ---- V permute (raw-reshape semantics): VT[nb*16+hh][dd][tt] =
//      VR[nb*1024 + hh*64 + (tt>>4)][(tt&15)*64 + dd]   (bias already in VR).
__global__ __launch_bounds__(256)
void transpose_v(const unsigned short* __restrict__ VR, unsigned short* __restrict__ VT) {
  __shared__ __align__(16) unsigned short tile[8][16][72];
  const int at = blockIdx.x;                 // 0..7
  const int hb = blockIdx.y;                 // nb*16+hh, 0..63
  const int nb = hb >> 4;
  const int tid = threadIdx.x;
  const size_t src = ((size_t)nb * 1024 + (size_t)(hb & 15) * 64 + (size_t)at * 8) * 1024;
#pragma unroll
  for (int p = 0; p < 4; p++) {
    const int idx = p * 256 + tid;           // 0..1023 (8 rows x 128 ush8)
    const int a = idx >> 7, c8 = idx & 127;
    *(ush8*)&tile[a][c8 >> 3][(c8 & 7) * 8] =
        *(const ush8*)&VR[src + (size_t)a * 1024 + (size_t)c8 * 8];
  }
  __syncthreads();
  const size_t dst = (size_t)hb * 65536 + (size_t)at * 128;
#pragma unroll
  for (int p = 0; p < 8; p++) {
    const int idx = p * 256 + tid;           // 0..2047 (64 dd x 32 tt4)
    const int dd = idx >> 5, q = idx & 31;
    ushort4 u;
    u.x = tile[(q * 4 + 0) >> 4][(q * 4 + 0) & 15][dd];
    u.y = tile[(q * 4 + 1) >> 4][(q * 4 + 1) & 15][dd];
    u.z = tile[(q * 4 + 2) >> 4][(q * 4 + 2) & 15][dd];
    u.w = tile[(q * 4 + 3) >> 4][(q * 4 + 3) & 15][dd];
    *(ushort4*)&VT[dst + (size_t)dd * 1024 + (size_t)q * 4] = u;
  }
}

// ---------------- GEMM: C = A(MxK') @ Bt(NxK')^T slice, bf16 MFMA, fused epilogues ------
// 128x128 tile, BK=32, 4 waves (2x2), 4x4 16x16x32 MFMA per wave. m97 structure.
// R8: XCD-bijective block swizzle (T1): default x-fastest dispatch spreads the 8
// blocks sharing an A-panel over 8 XCDs (each L2 re-fetches ~32 A-panels). Chunked
// remap gives each XCD a contiguous id range -> ~4 A-panels per XCD per GEMM.
// All grids used have (gx*gy)%8==0 so the simple bijective form applies.
template<int EPI>
__global__ __launch_bounds__(256, 2)
void gemm_bt(const unsigned short* __restrict__ A,
             const unsigned short* __restrict__ Bt,
             const float* __restrict__ bias,
             const float* __restrict__ bias2,
             const float* __restrict__ bias3,
             void* __restrict__ out, PtrQuad pq,
             int M, int N, int K, int ldk) {
  __shared__ unsigned short sA[128 * 32];
  __shared__ unsigned short sB[128 * 32];
  const int tid  = threadIdx.x;
  const int lane = tid & 63;
  const int wave = tid >> 6;
  const int l15  = lane & 15, l4 = lane >> 4;
  const int wr = wave >> 1, wc = wave & 1;

  const int gx = gridDim.x;
  const int nwg = gx * gridDim.y;
  int bid = blockIdx.y * gx + blockIdx.x;
  bid = (bid & 7) * (nwg >> 3) + (bid >> 3);       // XCD-chunked, bijective (nwg%8==0)
  const int bx = bid % gx, by = bid / gx;

  const long row0 = (long)by * 128;
  const long col0 = (long)bx * 128;
  const long k0   = (long)blockIdx.z * K;

  facc4 acc[4][4];
#pragma unroll
  for (int i = 0; i < 4; i++)
#pragma unroll
    for (int j = 0; j < 4; j++) acc[i][j] = (facc4)0.f;

  const int srow = tid >> 2;
  const int scol = (tid & 3) * 8;
  const unsigned short* Ap0 = A  + (row0 + srow) * (long)ldk + k0 + scol;
  const unsigned short* Ap1 = Ap0 + 64 * (long)ldk;
  const unsigned short* Bp0 = Bt + (col0 + srow) * (long)ldk + k0 + scol;
  const unsigned short* Bp1 = Bp0 + 64 * (long)ldk;
  const int wbase = (tid & ~63) * 8;
  unsigned short* sA0 = &sA[wbase];
  unsigned short* sA1 = &sA[2048 + wbase];
  unsigned short* sB0 = &sB[wbase];
  unsigned short* sB1 = &sB[2048 + wbase];

  const int aoff = (wr * 64 + l15) * 32 + l4 * 8;
  const int boff = (wc * 64 + l15) * 32 + l4 * 8;

  for (int kt = 0; kt < K; kt += 32) {
    gl2lds16(Ap0 + kt, sA0);
    gl2lds16(Ap1 + kt, sA1);
    gl2lds16(Bp0 + kt, sB0);
    gl2lds16(Bp1 + kt, sB1);
    __syncthreads();
    bfrag8 af[4], bf[4];
#pragma unroll
    for (int i = 0; i < 4; i++) af[i] = *(const bfrag8*)&sA[aoff + i * 512];
#pragma unroll
    for (int j = 0; j < 4; j++) bf[j] = *(const bfrag8*)&sB[boff + j * 512];
#pragma unroll
    for (int i = 0; i < 4; i++)
#pragma unroll
      for (int j = 0; j < 4; j++)
        acc[i][j] = __builtin_amdgcn_mfma_f32_16x16x32_bf16(af[i], bf[j], acc[i][j], 0, 0, 0);
    __syncthreads();
  }

#pragma unroll
  for (int i = 0; i < 4; i++) {
    const long m0 = row0 + wr * 64 + i * 16 + l4 * 4;
#pragma unroll
    for (int j = 0; j < 4; j++) {
      const long c = col0 + wc * 64 + j * 16 + l15;
      if constexpr (EPI == EPI_QKV) {
        const long which = c >> 10;
        const long cl = c & 1023;
        unsigned short* oq = (unsigned short*)out;
        if (which == 0) {
          const float bj = bias[cl];
#pragma unroll
          for (int r = 0; r < 4; r++)
            oq[(m0 + r) * 1024 + cl] = f2b((acc[i][j][r] + bj) * 0.03125f);
        } else if (which == 1) {
          const float bj = bias2[cl];
#pragma unroll
          for (int r = 0; r < 4; r++)
            (oq + 4194304)[(m0 + r) * 1024 + cl] = f2b(acc[i][j][r] + bj);
        } else {
          // V: coalesced row-major into VR; transpose_v applies the reshape permute
          const float bj = bias3[cl];
          unsigned short* vr = pq.p[0];
#pragma unroll
          for (int r = 0; r < 4; r++)
            vr[(m0 + r) * 1024 + cl] = f2b(acc[i][j][r] + bj);
        }
      } else if constexpr (EPI == EPI_F32) {
        const float bj = bias[c];
        float* of = (float*)out;
#pragma unroll
        for (int r = 0; r < 4; r++) of[(m0 + r) * (long)N + c] = acc[i][j][r] + bj;
      } else if constexpr (EPI == EPI_PART) {
        unsigned short* ob = pq.p[blockIdx.z];
#pragma unroll
        for (int r = 0; r < 4; r++) ob[(m0 + r) * (long)N + c] = f2b(acc[i][j][r]);
      } else {  // EPI_GELU -> bf16
        const float bj = bias[c];
        unsigned short* ob = (unsigned short*)out;
#pragma unroll
        for (int r = 0; r < 4; r++) {
          const float t = acc[i][j][r] + bj;
          ob[(m0 + r) * (long)N + c] = f2b(0.5f * t * (1.f + erff(t * 0.70710678f)));
        }
      }
    }
  }
}

// ---------------- fused attention v15: v14 + conflict-free denominator LDS ----------
// R7 counters: SQ_LDS_BANK_CONFLICT 2.1M/dispatch ~ 8.2k cy/CU ~ 10% of attn time.
// Address math: old stage-1 (ti1=tid>>4 -> 4 rows x 16 cols/wave @ stride-68) was
// ~8-way conflicted; Ds float4 writes ~4-way. v15: (a) stage-1 remapped to
// row=tid&31, col4=tid>>5 (32 rows/wave); (b) XOR swizzle on the column byte:
// byte(r,c4) = r*272 + ((c4*16) ^ ((r&7)<<4)) applied identically on Ds write,
// stage-1 read/Dt write, and stage-2 read -> ~2-way everywhere (free, G4/m136).
// Pw aliasing in Ds[w] unchanged (swizzle is a within-row permutation; same
// barrier-ordering argument).
__device__ __forceinline__ int dsw(int r, int c4) {
  return r * 272 + ((c4 * 16) ^ ((r & 7) << 4));
}

__global__ __launch_bounds__(512, 1)
void attn_kernel(const unsigned short* __restrict__ Qb,
                 const unsigned short* __restrict__ Kb,
                 const unsigned short* __restrict__ Vt,
                 PtrQuad APQ) {
  const int id = blockIdx.x;
  const int combo = id & 15;
  const int nb = combo & 3;
  const int sp = combo >> 2;                // 0..3 s-quarter
  const int tile = id >> 4;                 // 0..31 (32-row t-tiles)
  const int tid = threadIdx.x, lane = tid & 63;
  const int w = __builtin_amdgcn_readfirstlane(tid >> 6);
  const int l15 = lane & 15, l4 = lane >> 4;
  const int t0 = tile * 32;
  const int sbase = sp * 256;
  const int h0 = w * 2;                     // this wave's 2 heads

  __shared__ __align__(16) float Ds[8][32][68];   // 69.6 KB partials (Pw aliased in)
  __shared__ __align__(16) float Dt[32][68];      // 8.7 KB reduced denominators

  const size_t bb = ((size_t)(nb * 16)) << 16;
  const unsigned short* qB = Qb + bb;
  const unsigned short* kB = Kb + bb;
  const unsigned short* vB = Vt + bb;

  // ---- persistent Q B-frags (row = t = l15): 8 bfrag8 = 32 VGPRs ----
  bfrag8 qf[2][2][2];                       // [hh][ts][dh]
#pragma unroll
  for (int hh = 0; hh < 2; hh++)
#pragma unroll
    for (int ts = 0; ts < 2; ts++)
#pragma unroll
      for (int dh = 0; dh < 2; dh++)
        qf[hh][ts][dh] = *(const bfrag8*)(qB + ((size_t)(h0 + hh) << 16)
            + (size_t)(t0 + ts * 16 + l15) * 64 + dh * 32 + l4 * 8);

  const int swz = (l15 & 7) << 4;
  char* pw = (char*)&Ds[w][0][0];           // 2KB P bounce aliased in own Ds slot
  const int pwrow = l15 * 128;
  const int o1 = dsw(tid & 31, tid >> 5);   // stage-1 cell (swizzled byte offset)

  facc4 oacc[2][2][4];                      // [hh][ts][nt]
#pragma unroll
  for (int hh = 0; hh < 2; hh++)
#pragma unroll
    for (int ts = 0; ts < 2; ts++)
#pragma unroll
      for (int nt = 0; nt < 4; nt++) oacc[hh][ts][nt] = (facc4)0.f;

  for (int it = 0; it < 4; ++it) {
    const int s0 = sbase + it * 64;
    // ---- issue 16 K loads (independent b128, own heads only) ----
    bfrag8 kf[2][4][2];                     // [hh][ss][kh]
#pragma unroll
    for (int hh = 0; hh < 2; hh++) {
      const unsigned short* kh_ = kB + ((size_t)(h0 + hh) << 16) + (size_t)l15 * 64 + l4 * 8;
#pragma unroll
      for (int ss = 0; ss < 4; ss++)
#pragma unroll
        for (int kh = 0; kh < 2; kh++)
          kf[hh][ss][kh] = *(const bfrag8*)(kh_ + (size_t)(s0 + ss * 16) * 64 + kh * 32);
    }
    // ---- QK^T: C[row=s][col=t], Q persistent in regs ----
    facc4 sc[2][2][4];                      // [hh][ts][ss]
#pragma unroll
    for (int hh = 0; hh < 2; hh++)
#pragma unroll
      for (int ts = 0; ts < 2; ts++)
#pragma unroll
        for (int ss = 0; ss < 4; ss++) {
          facc4 a = __builtin_amdgcn_mfma_f32_16x16x32_bf16(kf[hh][ss][0], qf[hh][ts][0],
                                                            (facc4)0.f, 0, 0, 0);
          sc[hh][ts][ss] = __builtin_amdgcn_mfma_f32_16x16x32_bf16(kf[hh][ss][1],
                                                                   qf[hh][ts][1], a, 0, 0, 0);
        }
    // ---- issue 16 V loads (independent b128; consumed after both barriers) ----
    bfrag8 vf[2][2][4];                     // [hh][sk][nt]
#pragma unroll
    for (int hh = 0; hh < 2; hh++) {
      const unsigned short* vh_ = vB + ((size_t)(h0 + hh) << 16) + (size_t)l15 * 1024 + s0 + l4 * 8;
#pragma unroll
      for (int sk = 0; sk < 2; sk++)
#pragma unroll
        for (int nt = 0; nt < 4; nt++)
          vf[hh][sk][nt] = *(const bfrag8*)(vh_ + (size_t)(nt * 16) * 1024 + sk * 32);
    }
    // ---- exp + 2-head partial denominator -> Ds (8 float4 swizzled writes) ----
    facc4 dacc[2][4];                       // [ts][ss]
#pragma unroll
    for (int ts = 0; ts < 2; ts++)
#pragma unroll
      for (int ss = 0; ss < 4; ss++) dacc[ts][ss] = (facc4)0.f;
#pragma unroll
    for (int hh = 0; hh < 2; hh++)
#pragma unroll
      for (int ts = 0; ts < 2; ts++)
#pragma unroll
        for (int ss = 0; ss < 4; ss++)
#pragma unroll
          for (int r = 0; r < 4; r++) {
            const float e = __expf(sc[hh][ts][ss][r]);
            sc[hh][ts][ss][r] = e;
            dacc[ts][ss][r] += e;
          }
#pragma unroll
    for (int ts = 0; ts < 2; ts++)
#pragma unroll
      for (int ss = 0; ss < 4; ss++)
        *(facc4*)((char*)&Ds[w][0][0] + dsw(ts * 16 + l15, ss * 4 + l4)) = dacc[ts][ss];
    __syncthreads();                        // Ba: all 8 partials visible
    // ---- stage 1: each thread sums its cell over 8 waves (8 b128, ~2-way) ----
    {
      facc4 s_ = *(const facc4*)((const char*)&Ds[0][0][0] + o1);
#pragma unroll
      for (int ww = 1; ww < 8; ww++)
        s_ += *(const facc4*)((const char*)&Ds[0][0][0] + ww * 8704 + o1);
      *(facc4*)((char*)&Dt[0][0] + o1) = s_;
    }
    __syncthreads();                        // Bb: Dt visible; Ds[w] dead -> Pw usable
    // ---- stage 2: reciprocals from Dt (8 b128, ~2-way) ----
    facc4 rt[2][4];                         // [ts][ss]
#pragma unroll
    for (int ts = 0; ts < 2; ts++)
#pragma unroll
      for (int ss = 0; ss < 4; ss++) {
        const facc4 d = *(const facc4*)((const char*)&Dt[0][0] + dsw(ts * 16 + l15, ss * 4 + l4));
#pragma unroll
        for (int r = 0; r < 4; r++) rt[ts][ss][r] = __builtin_amdgcn_rcpf(d[r]);
      }
    // ---- normalize -> Pw bounce -> A-frags -> PV (wave-private, no barrier) ----
#pragma unroll
    for (int hh = 0; hh < 2; hh++)
#pragma unroll
      for (int ts = 0; ts < 2; ts++) {
#pragma unroll
        for (int ss = 0; ss < 4; ss++) {
          const float p0 = sc[hh][ts][ss][0] * rt[ts][ss][0];
          const float p1 = sc[hh][ts][ss][1] * rt[ts][ss][1];
          const float p2 = sc[hh][ts][ss][2] * rt[ts][ss][2];
          const float p3 = sc[hh][ts][ss][3] * rt[ts][ss][3];
          uint2 pk;
          asm("v_cvt_pk_bf16_f32 %0, %1, %2" : "=v"(pk.x) : "v"(p0), "v"(p1));
          asm("v_cvt_pk_bf16_f32 %0, %1, %2" : "=v"(pk.y) : "v"(p2), "v"(p3));
          *(uint2*)(pw + pwrow + ((ss * 32 + l4 * 8) ^ swz)) = pk;
        }
        const bfrag8 a0 = *(const bfrag8*)(pw + pwrow + ((l4 * 16) ^ swz));
        const bfrag8 a1 = *(const bfrag8*)(pw + pwrow + ((64 + l4 * 16) ^ swz));
#pragma unroll
        for (int nt = 0; nt < 4; nt++) {
          oacc[hh][ts][nt] = __builtin_amdgcn_mfma_f32_16x16x32_bf16(a0, vf[hh][0][nt],
                                                                    oacc[hh][ts][nt], 0, 0, 0);
          oacc[hh][ts][nt] = __builtin_amdgcn_mfma_f32_16x16x32_bf16(a1, vf[hh][1][nt],
                                                                    oacc[hh][ts][nt], 0, 0, 0);
        }
      }
  }

  // ---- bf16 partial O through the raw-reshape flat view ----
  unsigned short* P = APQ.p[sp];
#pragma unroll
  for (int hh = 0; hh < 2; hh++) {
    const size_t hb = ((size_t)nb << 20) + ((size_t)(h0 + hh) << 16);
#pragma unroll
    for (int ts = 0; ts < 2; ts++)
#pragma unroll
      for (int nt = 0; nt < 4; nt++)
#pragma unroll
        for (int r = 0; r < 4; r++)
          P[hb + (size_t)(t0 + ts * 16 + l4 * 4 + r) * 64 + nt * 16 + l15] =
              f2b(oacc[hh][ts][nt][r]);
  }
}

// ---------------- reduce 4 bf16 partials -> bf16 ----------------
__global__ __launch_bounds__(256)
void reduce_o4(PtrQuad pq, unsigned short* __restrict__ OB, int n4) {
  const int i = blockIdx.x * 256 + threadIdx.x;
  if (i < n4) {
    const ushort4 a = ((const ushort4*)pq.p[0])[i];
    const ushort4 b = ((const ushort4*)pq.p[1])[i];
    const ushort4 c = ((const ushort4*)pq.p[2])[i];
    const ushort4 d = ((const ushort4*)pq.p[3])[i];
    ushort4 u;
    u.x = f2b(b2f(a.x) + b2f(b.x) + b2f(c.x) + b2f(d.x));
    u.y = f2b(b2f(a.y) + b2f(b.y) + b2f(c.y) + b2f(d.y));
    u.z = f2b(b2f(a.z) + b2f(b.z) + b2f(c.z) + b2f(d.z));
    u.w = f2b(b2f(a.w) + b2f(b.w) + b2f(c.w) + b2f(d.w));
    ((ushort4*)OB)[i] = u;
  }
}

// ---- LayerNorm reducing 4 bf16 GEMM partials + bias + residual: out = LN(sum+b+res) ----
__global__ __launch_bounds__(256)
void ln_red(const unsigned short* __restrict__ P0, const unsigned short* __restrict__ P1,
            const unsigned short* __restrict__ P2, const unsigned short* __restrict__ P3,
            const float* __restrict__ bias, const float* __restrict__ resid,
            const float* __restrict__ g, const float* __restrict__ be,
            float* __restrict__ outf, unsigned short* __restrict__ outb) {
  const int row = blockIdx.x, tid = threadIdx.x;
  const size_t o4 = (size_t)row * 256 + tid;
  const ushort4 a = ((const ushort4*)P0)[o4];
  const ushort4 b = ((const ushort4*)P1)[o4];
  const ushort4 c = ((const ushort4*)P2)[o4];
  const ushort4 d = ((const ushort4*)P3)[o4];
  const float4 vb = ((const float4*)bias)[tid];
  const float4 vr = ((const float4*)resid)[o4];
  float t0 = b2f(a.x) + b2f(b.x) + b2f(c.x) + b2f(d.x) + vb.x + vr.x;
  float t1 = b2f(a.y) + b2f(b.y) + b2f(c.y) + b2f(d.y) + vb.y + vr.y;
  float t2 = b2f(a.z) + b2f(b.z) + b2f(c.z) + b2f(d.z) + vb.z + vr.z;
  float t3 = b2f(a.w) + b2f(b.w) + b2f(c.w) + b2f(d.w) + vb.w + vr.w;
  float s = t0 + t1 + t2 + t3;
  float q = t0 * t0 + t1 * t1 + t2 * t2 + t3 * t3;
#pragma unroll
  for (int off = 32; off > 0; off >>= 1) {
    s += __shfl_down(s, off, 64);
    q += __shfl_down(q, off, 64);
  }
  __shared__ float rs_[4], rq_[4];
  if ((tid & 63) == 0) { rs_[tid >> 6] = s; rq_[tid >> 6] = q; }
  __syncthreads();
  const float S = rs_[0] + rs_[1] + rs_[2] + rs_[3];
  const float Q = rq_[0] + rq_[1] + rq_[2] + rq_[3];
  const float mean = S * (1.f / 1024.f);
  const float var  = Q * (1.f / 1024.f) - mean * mean;
  const float rstd = rsqrtf(var + 1e-5f);
  const float4 vg  = ((const float4*)g)[tid];
  const float4 vbe = ((const float4*)be)[tid];
  float o0 = (t0 - mean) * rstd * vg.x + vbe.x;
  float o1 = (t1 - mean) * rstd * vg.y + vbe.y;
  float o2 = (t2 - mean) * rstd * vg.z + vbe.z;
  float o3 = (t3 - mean) * rstd * vg.w + vbe.w;
  ((float4*)(outf + (size_t)row * 1024))[tid] = make_float4(o0, o1, o2, o3);
  if (outb != nullptr) {
    ushort4 u;
    u.x = f2b(o0); u.y = f2b(o1); u.z = f2b(o2); u.w = f2b(o3);
    ((ushort4*)(outb + (size_t)row * 1024))[tid] = u;
  }
}

// ---------------- launch ----------------
extern "C" void kernel_launch(void* const* d_in, const int* in_sizes, int n_in,
                              void* d_out, int out_size, void* d_ws, size_t ws_size,
                              hipStream_t stream) {
  const float* x  = (const float*)d_in[0];
  const float* Wq = (const float*)d_in[1];
  const float* bq = (const float*)d_in[2];
  const float* Wk = (const float*)d_in[3];
  const float* bk = (const float*)d_in[4];
  const float* Wv = (const float*)d_in[5];
  const float* bv = (const float*)d_in[6];
  const float* Wo = (const float*)d_in[7];
  const float* bo = (const float*)d_in[8];
  const float* g1 = (const float*)d_in[9];
  const float* b1 = (const float*)d_in[10];
  const float* W1 = (const float*)d_in[11];
  const float* c1 = (const float*)d_in[12];
  const float* W2 = (const float*)d_in[13];
  const float* c2 = (const float*)d_in[14];
  const float* g2 = (const float*)d_in[15];
  const float* b2 = (const float*)d_in[16];
  float* out = (float*)d_out;

  char* ws = (char*)d_ws;
  unsigned short* XB  = (unsigned short*)(ws);              // 8MB  x bf16
  unsigned short* WQT = (unsigned short*)(ws + 8388608);    // 2MB
  unsigned short* WKT = (unsigned short*)(ws + 10485760);   // 2MB
  unsigned short* WVT = (unsigned short*)(ws + 12582912);   // 2MB
  unsigned short* WOT = (unsigned short*)(ws + 14680064);   // 2MB
  unsigned short* W1T = (unsigned short*)(ws + 16777216);   // 8MB
  unsigned short* W2T = (unsigned short*)(ws + 25165824);   // 8MB
  float*          X1  = (float*)(ws + 33554432);            // 16MB fp32 (LN1 out)
  unsigned short* X1B = (unsigned short*)(ws + 50331648);   // 8MB
  char* RB = ws + 58720256;                                 // 48MB union region
  unsigned short* QB  = (unsigned short*)(RB);              // 8MB
  unsigned short* KB  = (unsigned short*)(RB + 8388608);    // 8MB
  unsigned short* VT  = (unsigned short*)(RB + 16777216);   // 8MB
  unsigned short* OB  = (unsigned short*)(RB + 25165824);   // 8MB (VR before attn)
  unsigned short* VR  = OB;                                 // row-major V, dead after transpose_v
  unsigned short* H1B = (unsigned short*)(RB);              // 32MB FFN phase (= QB..OB)
  // attn bf16 partials: 2 in dead OWO region + 2 in X1 region (X1 written later)
  unsigned short* AP0 = (unsigned short*)(RB + 33554432);
  unsigned short* AP1 = (unsigned short*)(RB + 41943040);
  unsigned short* AP2 = (unsigned short*)(ws + 33554432);
  unsigned short* AP3 = (unsigned short*)(ws + 41943040);
  PtrQuad APQ = { { AP0, AP1, AP2, AP3 } };
  // o-proj split-K partials (QB/KB/VT free after attn; XB free after QKV)
  PtrQuad OPQ = { { QB, KB, VT, XB } };
  // FFN2 split-K partials (XB,X1B free; OWO region free)
  PtrQuad FPQ = { { XB, X1B, (unsigned short*)(RB + 33554432),
                    (unsigned short*)(RB + 41943040) } };
  PtrQuad VQ  = { { VR, nullptr, nullptr, nullptr } };
  PtrQuad ZQ  = { { nullptr, nullptr, nullptr, nullptr } };
  Ptr4f  Ws   = { { Wq, Wk, Wv, Wo } };
  PtrQuad WTs = { { WQT, WKT, WVT, WOT } };

  const dim3 tb(256);
  // fused prep: cvt + 6 weight transposes (1 launch instead of 7)
  prep_kernel<<<dim3(16384), tb, 0, stream>>>(x, XB, Ws, WTs, W1, W1T, W2, W2T);
  // QKV (N=3072): Q(scaled)/K coalesced; V row-major -> VR (scatter removed)
  gemm_bt<EPI_QKV><<<dim3(24, 32), tb, 0, stream>>>(XB, WQT, bq, bk, bv, (void*)QB, VQ,
                                                    4096, 3072, 1024, 1024);
  // V reshape-permute: VR -> VT (coalesced both sides)
  transpose_v<<<dim3(8, 64), tb, 0, stream>>>(VR, VT);
  // attention v15: 512 blocks x 512 thr, t32 tiles, 16 (nb,sp) combos, 4 partials
  attn_kernel<<<dim3(512), dim3(512), 0, stream>>>(QB, KB, VT, APQ);
  reduce_o4<<<dim3(4096), tb, 0, stream>>>(APQ, OB, 1048576);
  // O-proj: split-K=4 (kLen 256) -> bf16 partials; reduce+bias+residual fused in LN1
  gemm_bt<EPI_PART><<<dim3(8, 32, 4), tb, 0, stream>>>(OB, WOT, nullptr, nullptr, nullptr,
                                                       nullptr, OPQ, 4096, 1024, 256, 1024);
  ln_red<<<dim3(4096), tb, 0, stream>>>(QB, KB, VT, XB, bo, x, g1, b1, X1, X1B);
  // FFN1 + exact GELU -> bf16
  gemm_bt<EPI_GELU><<<dim3(32, 32), tb, 0, stream>>>(X1B, W1T, c1, nullptr, nullptr,
                                                     (void*)H1B, ZQ, 4096, 4096, 1024, 1024);
  // FFN2: split-K=4 (kLen 1024) -> bf16 partials; reduce+bias+residual fused in LN2
  gemm_bt<EPI_PART><<<dim3(8, 32, 4), tb, 0, stream>>>(H1B, W2T, nullptr, nullptr, nullptr,
                                                       nullptr, FPQ, 4096, 1024, 1024, 4096);
  ln_red<<<dim3(4096), tb, 0, stream>>>(FPQ.p[0], FPQ.p[1], FPQ.p[2], FPQ.p[3], c2, X1,
                                        g2, b2, out, (unsigned short*)nullptr);
}

// Round 9
// 385.973 us; speedup vs baseline: 1.0642x; 1.0642x over previous
//
#include <hip/hip_runtime.h>
#include <cstdint>
#include <cstddef>

#define EPI_QKV  0
#define EPI_F32  2
#define EPI_GELU 3
#define EPI_PART 4

typedef __attribute__((ext_vector_type(8))) short bfrag8;   // 8 bf16 (4 VGPRs)
typedef __attribute__((ext_vector_type(4))) float facc4;    // 4 fp32 acc
typedef __attribute__((ext_vector_type(8))) unsigned short ush8;

struct PtrQuad { unsigned short* p[4]; };
struct Ptr4f  { const float* p[4]; };

__device__ __forceinline__ unsigned short f2b(float x) {
  unsigned int u = __builtin_bit_cast(unsigned int, x);
  u += 0x7FFFu + ((u >> 16) & 1u);   // RNE
  return (unsigned short)(u >> 16);
}
__device__ __forceinline__ float b2f(unsigned short u) {
  unsigned int x = ((unsigned int)u) << 16;
  return __builtin_bit_cast(float, x);
}

__device__ __forceinline__ void gl2lds16(const unsigned short* g, unsigned short* l) {
  __builtin_amdgcn_global_load_lds(
      (const __attribute__((address_space(1))) unsigned int*)g,
      (__attribute__((address_space(3))) unsigned int*)l, 16, 0, 0);
}

// ---- fused prep: fp32->bf16 cvt of x + all 6 weight transposes in ONE launch ----
__device__ __forceinline__ void tr_tile(const float* __restrict__ in,
                                        unsigned short* __restrict__ out,
                                        int K, int N, int bx, int by,
                                        float (*tile)[33], int tid) {
  const int n0 = bx * 32, k0 = by * 32;
  const int tx = tid & 31, ty = tid >> 5;  // ty 0..7
#pragma unroll
  for (int i = 0; i < 32; i += 8)
    tile[ty + i][tx] = in[(size_t)(k0 + ty + i) * N + n0 + tx];
  __syncthreads();
#pragma unroll
  for (int i = 0; i < 32; i += 8)
    out[(size_t)(n0 + ty + i) * K + k0 + tx] = f2b(tile[tx][ty + i]);
}

__global__ __launch_bounds__(256)
void prep_kernel(const float* __restrict__ x, unsigned short* __restrict__ XB,
                 Ptr4f Ws, PtrQuad WTs,
                 const float* __restrict__ W1, unsigned short* __restrict__ W1T,
                 const float* __restrict__ W2, unsigned short* __restrict__ W2T) {
  __shared__ float tile[32][33];
  int b = blockIdx.x;
  const int tid = threadIdx.x;
  if (b < 4096) {                                  // cvt x -> bf16 (float4/ushort4)
    const int i = b * 256 + tid;
    const float4 v = ((const float4*)x)[i];
    ushort4 u;
    u.x = f2b(v.x); u.y = f2b(v.y); u.z = f2b(v.z); u.w = f2b(v.w);
    ((ushort4*)XB)[i] = u;
    return;
  }
  b -= 4096;
  if (b < 4096) {                                  // Wq/Wk/Wv/Wo: 1024x1024 each
    const int which = b >> 10, t = b & 1023;
    tr_tile(Ws.p[which], WTs.p[which], 1024, 1024, t & 31, t >> 5, tile, tid);
    return;
  }
  b -= 4096;
  if (b < 4096) {                                  // W1: K=1024, N=4096
    tr_tile(W1, W1T, 1024, 4096, b & 127, b >> 7, tile, tid);
    return;
  }
  b -= 4096;                                       // W2: K=4096, N=1024
  tr_tile(W2, W2T, 4096, 1024, b & 31, b >> 5, tile, tid);
}

// ---- V permute (raw-reshape semantics): VT[nb*16+hh][dd][tt] =
//      VR[nb*1024 + hh*64 + (tt>>4)][(tt&15)*64 + dd]   (bias already in VR).
__global__ __launch_bounds__(256)
void transpose_v(const unsigned short* __restrict__ VR, unsigned short* __restrict__ VT) {
  __shared__ __align__(16) unsigned short tile[8][16][72];
  const int at = blockIdx.x;                 // 0..7
  const int hb = blockIdx.y;                 // nb*16+hh, 0..63
  const int nb = hb >> 4;
  const int tid = threadIdx.x;
  const size_t src = ((size_t)nb * 1024 + (size_t)(hb & 15) * 64 + (size_t)at * 8) * 1024;
#pragma unroll
  for (int p = 0; p < 4; p++) {
    const int idx = p * 256 + tid;           // 0..1023 (8 rows x 128 ush8)
    const int a = idx >> 7, c8 = idx & 127;
    *(ush8*)&tile[a][c8 >> 3][(c8 & 7) * 8] =
        *(const ush8*)&VR[src + (size_t)a * 1024 + (size_t)c8 * 8];
  }
  __syncthreads();
  const size_t dst = (size_t)hb * 65536 + (size_t)at * 128;
#pragma unroll
  for (int p = 0; p < 8; p++) {
    const int idx = p * 256 + tid;           // 0..2047 (64 dd x 32 tt4)
    const int dd = idx >> 5, q = idx & 31;
    ushort4 u;
    u.x = tile[(q * 4 + 0) >> 4][(q * 4 + 0) & 15][dd];
    u.y = tile[(q * 4 + 1) >> 4][(q * 4 + 1) & 15][dd];
    u.z = tile[(q * 4 + 2) >> 4][(q * 4 + 2) & 15][dd];
    u.w = tile[(q * 4 + 3) >> 4][(q * 4 + 3) & 15][dd];
    *(ushort4*)&VT[dst + (size_t)dd * 1024 + (size_t)q * 4] = u;
  }
}

// ---------------- GEMM: C = A(MxK') @ Bt(NxK')^T slice, bf16 MFMA, fused epilogues ------
// 128x128 tile, BK=32, 4 waves (2x2), 4x4 16x16x32 MFMA per wave. m97 structure.
// SWZ: XCD-chunked bijective block remap -- applied ONLY to post-attn GEMMs
// (o-proj/FFN1/FFN2). R8 showed swizzling the QKV GEMM perturbs which XCD L2
// holds Q/K/V and slows attn (FETCH 26.6->36.4MB, +17us); post-attn GEMMs feed
// streaming consumers (ln_red) so that channel is closed. All grids (gx*gy)%8==0.
template<int EPI, bool SWZ>
__global__ __launch_bounds__(256, 2)
void gemm_bt(const unsigned short* __restrict__ A,
             const unsigned short* __restrict__ Bt,
             const float* __restrict__ bias,
             const float* __restrict__ bias2,
             const float* __restrict__ bias3,
             void* __restrict__ out, PtrQuad pq,
             int M, int N, int K, int ldk) {
  __shared__ unsigned short sA[128 * 32];
  __shared__ unsigned short sB[128 * 32];
  const int tid  = threadIdx.x;
  const int lane = tid & 63;
  const int wave = tid >> 6;
  const int l15  = lane & 15, l4 = lane >> 4;
  const int wr = wave >> 1, wc = wave & 1;

  int bx = blockIdx.x, by = blockIdx.y;
  if constexpr (SWZ) {
    const int gx = gridDim.x;
    const int nwg = gx * gridDim.y;
    int bid = by * gx + bx;
    bid = (bid & 7) * (nwg >> 3) + (bid >> 3);     // XCD-chunked, bijective (nwg%8==0)
    bx = bid % gx; by = bid / gx;
  }

  const long row0 = (long)by * 128;
  const long col0 = (long)bx * 128;
  const long k0   = (long)blockIdx.z * K;

  facc4 acc[4][4];
#pragma unroll
  for (int i = 0; i < 4; i++)
#pragma unroll
    for (int j = 0; j < 4; j++) acc[i][j] = (facc4)0.f;

  const int srow = tid >> 2;
  const int scol = (tid & 3) * 8;
  const unsigned short* Ap0 = A  + (row0 + srow) * (long)ldk + k0 + scol;
  const unsigned short* Ap1 = Ap0 + 64 * (long)ldk;
  const unsigned short* Bp0 = Bt + (col0 + srow) * (long)ldk + k0 + scol;
  const unsigned short* Bp1 = Bp0 + 64 * (long)ldk;
  const int wbase = (tid & ~63) * 8;
  unsigned short* sA0 = &sA[wbase];
  unsigned short* sA1 = &sA[2048 + wbase];
  unsigned short* sB0 = &sB[wbase];
  unsigned short* sB1 = &sB[2048 + wbase];

  const int aoff = (wr * 64 + l15) * 32 + l4 * 8;
  const int boff = (wc * 64 + l15) * 32 + l4 * 8;

  for (int kt = 0; kt < K; kt += 32) {
    gl2lds16(Ap0 + kt, sA0);
    gl2lds16(Ap1 + kt, sA1);
    gl2lds16(Bp0 + kt, sB0);
    gl2lds16(Bp1 + kt, sB1);
    __syncthreads();
    bfrag8 af[4], bf[4];
#pragma unroll
    for (int i = 0; i < 4; i++) af[i] = *(const bfrag8*)&sA[aoff + i * 512];
#pragma unroll
    for (int j = 0; j < 4; j++) bf[j] = *(const bfrag8*)&sB[boff + j * 512];
#pragma unroll
    for (int i = 0; i < 4; i++)
#pragma unroll
      for (int j = 0; j < 4; j++)
        acc[i][j] = __builtin_amdgcn_mfma_f32_16x16x32_bf16(af[i], bf[j], acc[i][j], 0, 0, 0);
    __syncthreads();
  }

#pragma unroll
  for (int i = 0; i < 4; i++) {
    const long m0 = row0 + wr * 64 + i * 16 + l4 * 4;
#pragma unroll
    for (int j = 0; j < 4; j++) {
      const long c = col0 + wc * 64 + j * 16 + l15;
      if constexpr (EPI == EPI_QKV) {
        const long which = c >> 10;
        const long cl = c & 1023;
        unsigned short* oq = (unsigned short*)out;
        if (which == 0) {
          const float bj = bias[cl];
#pragma unroll
          for (int r = 0; r < 4; r++)
            oq[(m0 + r) * 1024 + cl] = f2b((acc[i][j][r] + bj) * 0.03125f);
        } else if (which == 1) {
          const float bj = bias2[cl];
#pragma unroll
          for (int r = 0; r < 4; r++)
            (oq + 4194304)[(m0 + r) * 1024 + cl] = f2b(acc[i][j][r] + bj);
        } else {
          // V: coalesced row-major into VR; transpose_v applies the reshape permute
          const float bj = bias3[cl];
          unsigned short* vr = pq.p[0];
#pragma unroll
          for (int r = 0; r < 4; r++)
            vr[(m0 + r) * 1024 + cl] = f2b(acc[i][j][r] + bj);
        }
      } else if constexpr (EPI == EPI_F32) {
        const float bj = bias[c];
        float* of = (float*)out;
#pragma unroll
        for (int r = 0; r < 4; r++) of[(m0 + r) * (long)N + c] = acc[i][j][r] + bj;
      } else if constexpr (EPI == EPI_PART) {
        unsigned short* ob = pq.p[blockIdx.z];
#pragma unroll
        for (int r = 0; r < 4; r++) ob[(m0 + r) * (long)N + c] = f2b(acc[i][j][r]);
      } else {  // EPI_GELU -> bf16
        const float bj = bias[c];
        unsigned short* ob = (unsigned short*)out;
#pragma unroll
        for (int r = 0; r < 4; r++) {
          const float t = acc[i][j][r] + bj;
          ob[(m0 + r) * (long)N + c] = f2b(0.5f * t * (1.f + erff(t * 0.70710678f)));
        }
      }
    }
  }
}

// ---------------- fused attention v14 (EXACT R7 revert): ~82.6us, ~80% of the
// ~14 B/cy/CU L1-port ceiling for its 0.55GB L2 stream. R8's Ds swizzle made
// conflicts 4x WORSE (bank = 4*((k+(c4^k))mod 8) collapses lanes onto one quad)
// and is reverted wholesale. t64/wave cannot fit 256 VGPR with head-axis softmax.
__global__ __launch_bounds__(512, 1)
void attn_kernel(const unsigned short* __restrict__ Qb,
                 const unsigned short* __restrict__ Kb,
                 const unsigned short* __restrict__ Vt,
                 PtrQuad APQ) {
  const int id = blockIdx.x;
  const int combo = id & 15;
  const int nb = combo & 3;
  const int sp = combo >> 2;                // 0..3 s-quarter
  const int tile = id >> 4;                 // 0..31 (32-row t-tiles)
  const int tid = threadIdx.x, lane = tid & 63;
  const int w = __builtin_amdgcn_readfirstlane(tid >> 6);
  const int l15 = lane & 15, l4 = lane >> 4;
  const int t0 = tile * 32;
  const int sbase = sp * 256;
  const int h0 = w * 2;                     // this wave's 2 heads

  __shared__ __align__(16) float Ds[8][32][68];   // 69.6 KB partials (Pw aliased in)
  __shared__ __align__(16) float Dt[32][68];      // 8.7 KB reduced denominators

  const size_t bb = ((size_t)(nb * 16)) << 16;
  const unsigned short* qB = Qb + bb;
  const unsigned short* kB = Kb + bb;
  const unsigned short* vB = Vt + bb;

  // ---- persistent Q B-frags (row = t = l15): 8 bfrag8 = 32 VGPRs ----
  bfrag8 qf[2][2][2];                       // [hh][ts][dh]
#pragma unroll
  for (int hh = 0; hh < 2; hh++)
#pragma unroll
    for (int ts = 0; ts < 2; ts++)
#pragma unroll
      for (int dh = 0; dh < 2; dh++)
        qf[hh][ts][dh] = *(const bfrag8*)(qB + ((size_t)(h0 + hh) << 16)
            + (size_t)(t0 + ts * 16 + l15) * 64 + dh * 32 + l4 * 8);

  const int swz = (l15 & 7) << 4;
  char* pw = (char*)&Ds[w][0][0];           // 2KB P bounce aliased in own Ds slot
  const int pwrow = l15 * 128;
  const int ti1 = tid >> 4;                 // stage-1 cell row 0..31
  const int si1 = (tid & 15) * 4;           // stage-1 cell col (float4)

  facc4 oacc[2][2][4];                      // [hh][ts][nt]
#pragma unroll
  for (int hh = 0; hh < 2; hh++)
#pragma unroll
    for (int ts = 0; ts < 2; ts++)
#pragma unroll
      for (int nt = 0; nt < 4; nt++) oacc[hh][ts][nt] = (facc4)0.f;

  for (int it = 0; it < 4; ++it) {
    const int s0 = sbase + it * 64;
    // ---- issue 16 K loads (independent b128, own heads only) ----
    bfrag8 kf[2][4][2];                     // [hh][ss][kh]
#pragma unroll
    for (int hh = 0; hh < 2; hh++) {
      const unsigned short* kh_ = kB + ((size_t)(h0 + hh) << 16) + (size_t)l15 * 64 + l4 * 8;
#pragma unroll
      for (int ss = 0; ss < 4; ss++)
#pragma unroll
        for (int kh = 0; kh < 2; kh++)
          kf[hh][ss][kh] = *(const bfrag8*)(kh_ + (size_t)(s0 + ss * 16) * 64 + kh * 32);
    }
    // ---- QK^T: C[row=s][col=t], Q persistent in regs ----
    facc4 sc[2][2][4];                      // [hh][ts][ss]
#pragma unroll
    for (int hh = 0; hh < 2; hh++)
#pragma unroll
      for (int ts = 0; ts < 2; ts++)
#pragma unroll
        for (int ss = 0; ss < 4; ss++) {
          facc4 a = __builtin_amdgcn_mfma_f32_16x16x32_bf16(kf[hh][ss][0], qf[hh][ts][0],
                                                            (facc4)0.f, 0, 0, 0);
          sc[hh][ts][ss] = __builtin_amdgcn_mfma_f32_16x16x32_bf16(kf[hh][ss][1],
                                                                   qf[hh][ts][1], a, 0, 0, 0);
        }
    // ---- issue 16 V loads (independent b128; consumed after both barriers) ----
    bfrag8 vf[2][2][4];                     // [hh][sk][nt]
#pragma unroll
    for (int hh = 0; hh < 2; hh++) {
      const unsigned short* vh_ = vB + ((size_t)(h0 + hh) << 16) + (size_t)l15 * 1024 + s0 + l4 * 8;
#pragma unroll
      for (int sk = 0; sk < 2; sk++)
#pragma unroll
        for (int nt = 0; nt < 4; nt++)
          vf[hh][sk][nt] = *(const bfrag8*)(vh_ + (size_t)(nt * 16) * 1024 + sk * 32);
    }
    // ---- exp + 2-head partial denominator -> Ds (8 float4 writes) ----
    facc4 dacc[2][4];                       // [ts][ss]
#pragma unroll
    for (int ts = 0; ts < 2; ts++)
#pragma unroll
      for (int ss = 0; ss < 4; ss++) dacc[ts][ss] = (facc4)0.f;
#pragma unroll
    for (int hh = 0; hh < 2; hh++)
#pragma unroll
      for (int ts = 0; ts < 2; ts++)
#pragma unroll
        for (int ss = 0; ss < 4; ss++)
#pragma unroll
          for (int r = 0; r < 4; r++) {
            const float e = __expf(sc[hh][ts][ss][r]);
            sc[hh][ts][ss][r] = e;
            dacc[ts][ss][r] += e;
          }
#pragma unroll
    for (int ts = 0; ts < 2; ts++)
#pragma unroll
      for (int ss = 0; ss < 4; ss++)
        *(facc4*)&Ds[w][ts * 16 + l15][ss * 16 + l4 * 4] = dacc[ts][ss];
    __syncthreads();                        // Ba: all 8 partials visible
    // ---- stage 1: each thread sums its 4 cells over 8 waves (8 b128 reads) ----
    {
      facc4 s_ = *(const facc4*)&Ds[0][ti1][si1];
#pragma unroll
      for (int ww = 1; ww < 8; ww++) s_ += *(const facc4*)&Ds[ww][ti1][si1];
      *(facc4*)&Dt[ti1][si1] = s_;
    }
    __syncthreads();                        // Bb: Dt visible; Ds[w] dead -> Pw usable
    // ---- stage 2: reciprocals from Dt (8 b128 reads) ----
    facc4 rt[2][4];                         // [ts][ss]
#pragma unroll
    for (int ts = 0; ts < 2; ts++)
#pragma unroll
      for (int ss = 0; ss < 4; ss++) {
        const facc4 d = *(const facc4*)&Dt[ts * 16 + l15][ss * 16 + l4 * 4];
#pragma unroll
        for (int r = 0; r < 4; r++) rt[ts][ss][r] = __builtin_amdgcn_rcpf(d[r]);
      }
    // ---- normalize -> Pw bounce -> A-frags -> PV (wave-private, no barrier) ----
#pragma unroll
    for (int hh = 0; hh < 2; hh++)
#pragma unroll
      for (int ts = 0; ts < 2; ts++) {
#pragma unroll
        for (int ss = 0; ss < 4; ss++) {
          const float p0 = sc[hh][ts][ss][0] * rt[ts][ss][0];
          const float p1 = sc[hh][ts][ss][1] * rt[ts][ss][1];
          const float p2 = sc[hh][ts][ss][2] * rt[ts][ss][2];
          const float p3 = sc[hh][ts][ss][3] * rt[ts][ss][3];
          uint2 pk;
          asm("v_cvt_pk_bf16_f32 %0, %1, %2" : "=v"(pk.x) : "v"(p0), "v"(p1));
          asm("v_cvt_pk_bf16_f32 %0, %1, %2" : "=v"(pk.y) : "v"(p2), "v"(p3));
          *(uint2*)(pw + pwrow + ((ss * 32 + l4 * 8) ^ swz)) = pk;
        }
        const bfrag8 a0 = *(const bfrag8*)(pw + pwrow + ((l4 * 16) ^ swz));
        const bfrag8 a1 = *(const bfrag8*)(pw + pwrow + ((64 + l4 * 16) ^ swz));
#pragma unroll
        for (int nt = 0; nt < 4; nt++) {
          oacc[hh][ts][nt] = __builtin_amdgcn_mfma_f32_16x16x32_bf16(a0, vf[hh][0][nt],
                                                                    oacc[hh][ts][nt], 0, 0, 0);
          oacc[hh][ts][nt] = __builtin_amdgcn_mfma_f32_16x16x32_bf16(a1, vf[hh][1][nt],
                                                                    oacc[hh][ts][nt], 0, 0, 0);
        }
      }
  }

  // ---- bf16 partial O through the raw-reshape flat view ----
  unsigned short* P = APQ.p[sp];
#pragma unroll
  for (int hh = 0; hh < 2; hh++) {
    const size_t hb = ((size_t)nb << 20) + ((size_t)(h0 + hh) << 16);
#pragma unroll
    for (int ts = 0; ts < 2; ts++)
#pragma unroll
      for (int nt = 0; nt < 4; nt++)
#pragma unroll
        for (int r = 0; r < 4; r++)
          P[hb + (size_t)(t0 + ts * 16 + l4 * 4 + r) * 64 + nt * 16 + l15] =
              f2b(oacc[hh][ts][nt][r]);
  }
}

// ---------------- reduce 4 bf16 partials -> bf16 ----------------
__global__ __launch_bounds__(256)
void reduce_o4(PtrQuad pq, unsigned short* __restrict__ OB, int n4) {
  const int i = blockIdx.x * 256 + threadIdx.x;
  if (i < n4) {
    const ushort4 a = ((const ushort4*)pq.p[0])[i];
    const ushort4 b = ((const ushort4*)pq.p[1])[i];
    const ushort4 c = ((const ushort4*)pq.p[2])[i];
    const ushort4 d = ((const ushort4*)pq.p[3])[i];
    ushort4 u;
    u.x = f2b(b2f(a.x) + b2f(b.x) + b2f(c.x) + b2f(d.x));
    u.y = f2b(b2f(a.y) + b2f(b.y) + b2f(c.y) + b2f(d.y));
    u.z = f2b(b2f(a.z) + b2f(b.z) + b2f(c.z) + b2f(d.z));
    u.w = f2b(b2f(a.w) + b2f(b.w) + b2f(c.w) + b2f(d.w));
    ((ushort4*)OB)[i] = u;
  }
}

// ---- LayerNorm reducing 4 bf16 GEMM partials + bias + residual: out = LN(sum+b+res) ----
__global__ __launch_bounds__(256)
void ln_red(const unsigned short* __restrict__ P0, const unsigned short* __restrict__ P1,
            const unsigned short* __restrict__ P2, const unsigned short* __restrict__ P3,
            const float* __restrict__ bias, const float* __restrict__ resid,
            const float* __restrict__ g, const float* __restrict__ be,
            float* __restrict__ outf, unsigned short* __restrict__ outb) {
  const int row = blockIdx.x, tid = threadIdx.x;
  const size_t o4 = (size_t)row * 256 + tid;
  const ushort4 a = ((const ushort4*)P0)[o4];
  const ushort4 b = ((const ushort4*)P1)[o4];
  const ushort4 c = ((const ushort4*)P2)[o4];
  const ushort4 d = ((const ushort4*)P3)[o4];
  const float4 vb = ((const float4*)bias)[tid];
  const float4 vr = ((const float4*)resid)[o4];
  float t0 = b2f(a.x) + b2f(b.x) + b2f(c.x) + b2f(d.x) + vb.x + vr.x;
  float t1 = b2f(a.y) + b2f(b.y) + b2f(c.y) + b2f(d.y) + vb.y + vr.y;
  float t2 = b2f(a.z) + b2f(b.z) + b2f(c.z) + b2f(d.z) + vb.z + vr.z;
  float t3 = b2f(a.w) + b2f(b.w) + b2f(c.w) + b2f(d.w) + vb.w + vr.w;
  float s = t0 + t1 + t2 + t3;
  float q = t0 * t0 + t1 * t1 + t2 * t2 + t3 * t3;
#pragma unroll
  for (int off = 32; off > 0; off >>= 1) {
    s += __shfl_down(s, off, 64);
    q += __shfl_down(q, off, 64);
  }
  __shared__ float rs_[4], rq_[4];
  if ((tid & 63) == 0) { rs_[tid >> 6] = s; rq_[tid >> 6] = q; }
  __syncthreads();
  const float S = rs_[0] + rs_[1] + rs_[2] + rs_[3];
  const float Q = rq_[0] + rq_[1] + rq_[2] + rq_[3];
  const float mean = S * (1.f / 1024.f);
  const float var  = Q * (1.f / 1024.f) - mean * mean;
  const float rstd = rsqrtf(var + 1e-5f);
  const float4 vg  = ((const float4*)g)[tid];
  const float4 vbe = ((const float4*)be)[tid];
  float o0 = (t0 - mean) * rstd * vg.x + vbe.x;
  float o1 = (t1 - mean) * rstd * vg.y + vbe.y;
  float o2 = (t2 - mean) * rstd * vg.z + vbe.z;
  float o3 = (t3 - mean) * rstd * vg.w + vbe.w;
  ((float4*)(outf + (size_t)row * 1024))[tid] = make_float4(o0, o1, o2, o3);
  if (outb != nullptr) {
    ushort4 u;
    u.x = f2b(o0); u.y = f2b(o1); u.z = f2b(o2); u.w = f2b(o3);
    ((ushort4*)(outb + (size_t)row * 1024))[tid] = u;
  }
}

// ---------------- launch ----------------
extern "C" void kernel_launch(void* const* d_in, const int* in_sizes, int n_in,
                              void* d_out, int out_size, void* d_ws, size_t ws_size,
                              hipStream_t stream) {
  const float* x  = (const float*)d_in[0];
  const float* Wq = (const float*)d_in[1];
  const float* bq = (const float*)d_in[2];
  const float* Wk = (const float*)d_in[3];
  const float* bk = (const float*)d_in[4];
  const float* Wv = (const float*)d_in[5];
  const float* bv = (const float*)d_in[6];
  const float* Wo = (const float*)d_in[7];
  const float* bo = (const float*)d_in[8];
  const float* g1 = (const float*)d_in[9];
  const float* b1 = (const float*)d_in[10];
  const float* W1 = (const float*)d_in[11];
  const float* c1 = (const float*)d_in[12];
  const float* W2 = (const float*)d_in[13];
  const float* c2 = (const float*)d_in[14];
  const float* g2 = (const float*)d_in[15];
  const float* b2 = (const float*)d_in[16];
  float* out = (float*)d_out;

  char* ws = (char*)d_ws;
  unsigned short* XB  = (unsigned short*)(ws);              // 8MB  x bf16
  unsigned short* WQT = (unsigned short*)(ws + 8388608);    // 2MB
  unsigned short* WKT = (unsigned short*)(ws + 10485760);   // 2MB
  unsigned short* WVT = (unsigned short*)(ws + 12582912);   // 2MB
  unsigned short* WOT = (unsigned short*)(ws + 14680064);   // 2MB
  unsigned short* W1T = (unsigned short*)(ws + 16777216);   // 8MB
  unsigned short* W2T = (unsigned short*)(ws + 25165824);   // 8MB
  float*          X1  = (float*)(ws + 33554432);            // 16MB fp32 (LN1 out)
  unsigned short* X1B = (unsigned short*)(ws + 50331648);   // 8MB
  char* RB = ws + 58720256;                                 // 48MB union region
  unsigned short* QB  = (unsigned short*)(RB);              // 8MB
  unsigned short* KB  = (unsigned short*)(RB + 8388608);    // 8MB
  unsigned short* VT  = (unsigned short*)(RB + 16777216);   // 8MB
  unsigned short* OB  = (unsigned short*)(RB + 25165824);   // 8MB (VR before attn)
  unsigned short* VR  = OB;                                 // row-major V, dead after transpose_v
  unsigned short* H1B = (unsigned short*)(RB);              // 32MB FFN phase (= QB..OB)
  // attn bf16 partials: 2 in dead OWO region + 2 in X1 region (X1 written later)
  unsigned short* AP0 = (unsigned short*)(RB + 33554432);
  unsigned short* AP1 = (unsigned short*)(RB + 41943040);
  unsigned short* AP2 = (unsigned short*)(ws + 33554432);
  unsigned short* AP3 = (unsigned short*)(ws + 41943040);
  PtrQuad APQ = { { AP0, AP1, AP2, AP3 } };
  // o-proj split-K partials (QB/KB/VT free after attn; XB free after QKV)
  PtrQuad OPQ = { { QB, KB, VT, XB } };
  // FFN2 split-K partials (XB,X1B free; OWO region free)
  PtrQuad FPQ = { { XB, X1B, (unsigned short*)(RB + 33554432),
                    (unsigned short*)(RB + 41943040) } };
  PtrQuad VQ  = { { VR, nullptr, nullptr, nullptr } };
  PtrQuad ZQ  = { { nullptr, nullptr, nullptr, nullptr } };
  Ptr4f  Ws   = { { Wq, Wk, Wv, Wo } };
  PtrQuad WTs = { { WQT, WKT, WVT, WOT } };

  const dim3 tb(256);
  // fused prep: cvt + 6 weight transposes (1 launch instead of 7)
  prep_kernel<<<dim3(16384), tb, 0, stream>>>(x, XB, Ws, WTs, W1, W1T, W2, W2T);
  // QKV (N=3072): Q(scaled)/K coalesced; V row-major -> VR. NO swizzle (R8 lesson).
  gemm_bt<EPI_QKV, false><<<dim3(24, 32), tb, 0, stream>>>(XB, WQT, bq, bk, bv, (void*)QB, VQ,
                                                           4096, 3072, 1024, 1024);
  // V reshape-permute: VR -> VT (coalesced both sides)
  transpose_v<<<dim3(8, 64), tb, 0, stream>>>(VR, VT);
  // attention v14 (R7-exact): 512 blocks x 512 thr, t32 tiles, 16 combos, 4 partials
  attn_kernel<<<dim3(512), dim3(512), 0, stream>>>(QB, KB, VT, APQ);
  reduce_o4<<<dim3(4096), tb, 0, stream>>>(APQ, OB, 1048576);
  // O-proj: split-K=4 -> bf16 partials; XCD swizzle ON (post-attn, streaming consumer)
  gemm_bt<EPI_PART, true><<<dim3(8, 32, 4), tb, 0, stream>>>(OB, WOT, nullptr, nullptr, nullptr,
                                                             nullptr, OPQ, 4096, 1024, 256, 1024);
  ln_red<<<dim3(4096), tb, 0, stream>>>(QB, KB, VT, XB, bo, x, g1, b1, X1, X1B);
  // FFN1 + exact GELU -> bf16; XCD swizzle ON
  gemm_bt<EPI_GELU, true><<<dim3(32, 32), tb, 0, stream>>>(X1B, W1T, c1, nullptr, nullptr,
                                                           (void*)H1B, ZQ, 4096, 4096, 1024, 1024);
  // FFN2: split-K=4 -> bf16 partials; XCD swizzle ON
  gemm_bt<EPI_PART, true><<<dim3(8, 32, 4), tb, 0, stream>>>(H1B, W2T, nullptr, nullptr, nullptr,
                                                             nullptr, FPQ, 4096, 1024, 1024, 4096);
  ln_red<<<dim3(4096), tb, 0, stream>>>(FPQ.p[0], FPQ.p[1], FPQ.p[2], FPQ.p[3], c2, X1,
                                        g2, b2, out, (unsigned short*)nullptr);
}